// Round 1
// baseline (255.745 us; speedup 1.0000x reference)
//
#include <hip/hip_runtime.h>

// Problem constants (from reference): B=12288, D=256, N_SUBSETS=3, m=4096,
// 64 classes, EPS=1e-8, WEIGHT=1.0.
//
// Algebraic identity: pair_sum_s = sum_c (P_c . Z_c) - sum_i pn_i.zn_i
// where P_c = sum of normalized p rows in class c (per subset), Z_c likewise.
// This turns the 3x(4096x4096x256) GEMM into a single streaming pass.

#define D 256
#define NSUB 3
#define NCLS 64
#define MROWS 4096  // rows per subset

// Workspace layout (zeroed via hipMemsetAsync each launch):
//   P[NSUB][NCLS][D]  float   : 49152 f32  @ offset 0        (196608 B)
//   Z[NSUB][NCLS][D]  float   : 49152 f32  @ 196608          (196608 B)
//   diag[NSUB]        double  : 3 f64      @ 393216          (24 B)
//   counts[NSUB*NCLS] int     : 192 i32    @ 393240          (768 B)
#define WS_P_OFF     0
#define WS_Z_OFF     196608
#define WS_DIAG_OFF  393216
#define WS_CNT_OFF   393240
#define WS_TOTAL     394008

__global__ void __launch_bounds__(256)
simsiam_rows(const float* __restrict__ ps, const float* __restrict__ zs,
             const int* __restrict__ targets,
             float* __restrict__ Psum, float* __restrict__ Zsum,
             double* __restrict__ diag, int* __restrict__ counts) {
    const int i = blockIdx.x;     // row 0..B-1
    const int d = threadIdx.x;    // dim 0..255
    const int s = i >> 12;        // i / 4096 -> subset

    const float p = ps[i * D + d];
    const float z = zs[i * D + d];

    // Reduce three sums across the 256-thread block: p*p, z*z, p*z.
    float sp = p * p, sz = z * z, pz = p * z;
    #pragma unroll
    for (int off = 32; off > 0; off >>= 1) {
        sp += __shfl_down(sp, off, 64);
        sz += __shfl_down(sz, off, 64);
        pz += __shfl_down(pz, off, 64);
    }
    __shared__ float ssp[4], ssz[4], spz[4];
    const int wave = d >> 6;
    if ((d & 63) == 0) { ssp[wave] = sp; ssz[wave] = sz; spz[wave] = pz; }
    __syncthreads();
    const float tsp = ssp[0] + ssp[1] + ssp[2] + ssp[3];
    const float tsz = ssz[0] + ssz[1] + ssz[2] + ssz[3];
    const float tpz = spz[0] + spz[1] + spz[2] + spz[3];

    const float invp = 1.0f / fmaxf(sqrtf(tsp), 1e-8f);
    const float invz = 1.0f / fmaxf(sqrtf(tsz), 1e-8f);

    const int c = targets[i];
    const int base = (s * NCLS + c) * D + d;
    atomicAdd(&Psum[base], p * invp);
    atomicAdd(&Zsum[base], z * invz);

    if (d == 0) {
        atomicAdd(&diag[s], (double)tpz * (double)invp * (double)invz);
        atomicAdd(&counts[s * NCLS + c], 1);
    }
}

__global__ void __launch_bounds__(256)
simsiam_finish(const float* __restrict__ Psum, const float* __restrict__ Zsum,
               const double* __restrict__ diag, const int* __restrict__ counts,
               float* __restrict__ out) {
    const int t = threadIdx.x;  // 0..255 (= dim index)
    double local[NSUB] = {0.0, 0.0, 0.0};
    #pragma unroll
    for (int s = 0; s < NSUB; s++) {
        for (int c = 0; c < NCLS; c++) {
            const int idx = (s * NCLS + c) * D + t;
            local[s] += (double)Psum[idx] * (double)Zsum[idx];
        }
    }
    __shared__ double red[NSUB][256];
    #pragma unroll
    for (int s = 0; s < NSUB; s++) red[s][t] = local[s];
    __syncthreads();
    for (int step = 128; step > 0; step >>= 1) {
        if (t < step) {
            #pragma unroll
            for (int s = 0; s < NSUB; s++) red[s][t] += red[s][t + step];
        }
        __syncthreads();
    }
    if (t == 0) {
        double acc = 0.0;
        #pragma unroll
        for (int s = 0; s < NSUB; s++) {
            long long cnt = 0;
            for (int c = 0; c < NCLS; c++) {
                const long long k = counts[s * NCLS + c];
                cnt += k * (k - 1) / 2;
            }
            const double pair = red[s][0] - diag[s];
            acc += -0.5 * pair / (double)cnt;
        }
        out[0] = (float)(acc / (double)NSUB);
    }
}

extern "C" void kernel_launch(void* const* d_in, const int* in_sizes, int n_in,
                              void* d_out, int out_size, void* d_ws, size_t ws_size,
                              hipStream_t stream) {
    const float* ps = (const float*)d_in[0];
    const float* zs = (const float*)d_in[1];
    const int* targets = (const int*)d_in[2];

    char* ws = (char*)d_ws;
    float*  Psum   = (float*)(ws + WS_P_OFF);
    float*  Zsum   = (float*)(ws + WS_Z_OFF);
    double* diag   = (double*)(ws + WS_DIAG_OFF);
    int*    counts = (int*)(ws + WS_CNT_OFF);

    // Workspace is poisoned 0xAA before every launch — zero our accumulators.
    hipMemsetAsync(d_ws, 0, WS_TOTAL, stream);

    const int B = in_sizes[0] / D;  // 12288
    simsiam_rows<<<B, D, 0, stream>>>(ps, zs, targets, Psum, Zsum, diag, counts);
    simsiam_finish<<<1, D, 0, stream>>>(Psum, Zsum, diag, counts, (float*)d_out);
}

// Round 2
// 122.143 us; speedup vs baseline: 2.0938x; 2.0938x over previous
//
#include <hip/hip_runtime.h>

// B=12288, D=256, N_SUBSETS=3, m=4096, 64 classes, EPS=1e-8, WEIGHT=1.0.
//
// pair_sum_s = sum_c dot(P_c, Z_c) - sum_i pn_i.zn_i   (P_c = sum of pn rows in class c)
// loss = mean_s( -0.5 * pair_sum_s / cnt_s )
//
// R2: no global fp32 atomics. Block (s,c) owns class c of subset s; P_c, Z_c
// accumulate in registers (thread d = dim d). Row lists built in phase1 with
// one int atomic per row (12288 atomics to 192 counters - cheap).

#define D     256
#define NSUB  3
#define NCLS  64
#define M     4096
#define B_TOT 12288
#define CAP   256   // rowlist capacity per (s,c); mean 64, 8-sigma ~128

// ws layout:
//   cnt[192]            int     @ 0        (768 B)    <- memset 0
//   rowlist[192][CAP]   int     @ 768      (196608 B)
//   invp[12288]         float   @ 197376   (49152 B)
//   invz[12288]         float   @ 246528   (49152 B)
//   diagpart[3072]      double  @ 295680   (24576 B)
//   pairdot[192]        double  @ 320256   (1536 B)
#define WS_CNT     0
#define WS_RL      768
#define WS_INVP    197376
#define WS_INVZ    246528
#define WS_DIAG    295680
#define WS_PDOT    320256

__global__ void __launch_bounds__(256)
phase1(const float* __restrict__ ps, const float* __restrict__ zs,
       const int* __restrict__ targets,
       int* __restrict__ cnt, int* __restrict__ rowlist,
       float* __restrict__ invp, float* __restrict__ invz,
       double* __restrict__ diagpart) {
    const int b    = blockIdx.x;        // 0..767, 16 rows per block
    const int t    = threadIdx.x;
    const int w    = t >> 6;            // wave 0..3
    const int lane = t & 63;

    double dloc = 0.0;
    #pragma unroll
    for (int j = 0; j < 4; ++j) {
        const int row = b * 16 + w * 4 + j;           // one wave per row
        const float4 p4 = ((const float4*)ps)[row * 64 + lane];
        const float4 z4 = ((const float4*)zs)[row * 64 + lane];
        float sp = p4.x*p4.x + p4.y*p4.y + p4.z*p4.z + p4.w*p4.w;
        float sz = z4.x*z4.x + z4.y*z4.y + z4.z*z4.z + z4.w*z4.w;
        float pz = p4.x*z4.x + p4.y*z4.y + p4.z*z4.z + p4.w*z4.w;
        #pragma unroll
        for (int off = 32; off > 0; off >>= 1) {
            sp += __shfl_down(sp, off, 64);
            sz += __shfl_down(sz, off, 64);
            pz += __shfl_down(pz, off, 64);
        }
        if (lane == 0) {
            const float ip = 1.0f / fmaxf(sqrtf(sp), 1e-8f);
            const float iz = 1.0f / fmaxf(sqrtf(sz), 1e-8f);
            invp[row] = ip;
            invz[row] = iz;
            dloc += (double)pz * (double)ip * (double)iz;
            const int s = row >> 12;
            const int c = targets[row];
            const int slot = atomicAdd(&cnt[s * NCLS + c], 1);
            if (slot < CAP) rowlist[(s * NCLS + c) * CAP + slot] = row;
        }
    }
    if (lane == 0) diagpart[b * 4 + w] = dloc;   // s = index/1024
}

__global__ void __launch_bounds__(256)
phase2(const float* __restrict__ ps, const float* __restrict__ zs,
       const int* __restrict__ cnt, const int* __restrict__ rowlist,
       const float* __restrict__ invp, const float* __restrict__ invz,
       double* __restrict__ pairdot) {
    const int sc = blockIdx.x;   // 0..191 = s*64 + c
    const int t  = threadIdx.x;  // dim 0..255

    int k = cnt[sc];
    if (k > CAP) k = CAP;
    const int* rl = rowlist + sc * CAP;

    float P = 0.0f, Z = 0.0f;
    for (int j = 0; j < k; ++j) {
        const int row = rl[j];
        P += ps[row * D + t] * invp[row];
        Z += zs[row * D + t] * invz[row];
    }

    double dot = (double)P * (double)Z;
    #pragma unroll
    for (int off = 32; off > 0; off >>= 1)
        dot += __shfl_down(dot, off, 64);
    __shared__ double sred[4];
    if ((t & 63) == 0) sred[t >> 6] = dot;
    __syncthreads();
    if (t == 0) pairdot[sc] = sred[0] + sred[1] + sred[2] + sred[3];
}

__global__ void __launch_bounds__(256)
finish(const double* __restrict__ pairdot, const double* __restrict__ diagpart,
       const int* __restrict__ cnt, float* __restrict__ out) {
    const int t    = threadIdx.x;
    const int w    = t >> 6;
    const int lane = t & 63;

    // pairdot & pair counts: threads 0..191; wave w == subset w for w<3.
    double dotv = 0.0, c2 = 0.0;
    if (t < NSUB * NCLS) {
        dotv = pairdot[t];
        const double kk = (double)cnt[t];
        c2 = kk * (kk - 1.0) * 0.5;
    }
    // diag partials: 3072 doubles, subset = index/1024 = q>>2 (uniform per q).
    double dg[NSUB] = {0.0, 0.0, 0.0};
    #pragma unroll
    for (int q = 0; q < 12; ++q)
        dg[q >> 2] += diagpart[q * 256 + t];

    #pragma unroll
    for (int off = 32; off > 0; off >>= 1) {
        dotv += __shfl_down(dotv, off, 64);
        c2   += __shfl_down(c2, off, 64);
        #pragma unroll
        for (int s = 0; s < NSUB; ++s) dg[s] += __shfl_down(dg[s], off, 64);
    }

    __shared__ double wdot[4], wc2[4], wdg[NSUB][4];
    if (lane == 0) {
        wdot[w] = dotv;
        wc2[w]  = c2;
        #pragma unroll
        for (int s = 0; s < NSUB; ++s) wdg[s][w] = dg[s];
    }
    __syncthreads();
    if (t == 0) {
        double acc = 0.0;
        #pragma unroll
        for (int s = 0; s < NSUB; ++s) {
            const double diag_s = wdg[s][0] + wdg[s][1] + wdg[s][2] + wdg[s][3];
            const double pair_s = wdot[s] - diag_s;   // wave s held subset s
            acc += -0.5 * pair_s / wc2[s];
        }
        out[0] = (float)(acc / (double)NSUB);
    }
}

extern "C" void kernel_launch(void* const* d_in, const int* in_sizes, int n_in,
                              void* d_out, int out_size, void* d_ws, size_t ws_size,
                              hipStream_t stream) {
    const float* ps      = (const float*)d_in[0];
    const float* zs      = (const float*)d_in[1];
    const int*   targets = (const int*)d_in[2];

    char* ws = (char*)d_ws;
    int*    cnt      = (int*)(ws + WS_CNT);
    int*    rowlist  = (int*)(ws + WS_RL);
    float*  invp     = (float*)(ws + WS_INVP);
    float*  invz     = (float*)(ws + WS_INVZ);
    double* diagpart = (double*)(ws + WS_DIAG);
    double* pairdot  = (double*)(ws + WS_PDOT);

    hipMemsetAsync(cnt, 0, NSUB * NCLS * sizeof(int), stream);

    phase1<<<B_TOT / 16, 256, 0, stream>>>(ps, zs, targets, cnt, rowlist,
                                           invp, invz, diagpart);
    phase2<<<NSUB * NCLS, 256, 0, stream>>>(ps, zs, cnt, rowlist,
                                            invp, invz, pairdot);
    finish<<<1, 256, 0, stream>>>(pairdot, diagpart, cnt, (float*)d_out);
}

// Round 3
// 102.732 us; speedup vs baseline: 2.4894x; 1.1890x over previous
//
#include <hip/hip_runtime.h>

// B=12288, D=256, N_SUBSETS=3, m=4096, 64 classes, EPS=1e-8, WEIGHT=1.0.
//
// pair_sum_s = sum_c dot(P_c, Z_c) - sum_i pn_i.zn_i   (P_c = sum of pn rows in class c)
// loss = mean_s( -0.5 * pair_sum_s / cnt_s )
//
// R3: phase2 latency fix — rowlist/inv-norms staged in LDS, each (s,c) class
// split across 4 blocks (768 blocks = 3/CU), inner loop unrolled x4 so 8
// independent row loads are in flight. Note: ~86 us of measured dur is the
// harness's 256 MiB d_ws poison fill (2 x 43 us fillBufferAligned), not us.

#define D      256
#define NSUB   3
#define NCLS   64
#define B_TOT  12288
#define CAP    256   // rowlist capacity per (s,c); mean 64, max ~100
#define SPLIT  4     // blocks per (s,c) in phase2
#define NPD    (NSUB * NCLS * SPLIT)   // 768 partial dots

// ws layout:
//   cnt[192]            int     @ 0        (768 B)    <- memset 0
//   rowlist[192][CAP]   int     @ 768      (196608 B)
//   invp[12288]         float   @ 197376   (49152 B)
//   invz[12288]         float   @ 246528   (49152 B)
//   diagpart[3072]      double  @ 295680   (24576 B)
//   pairdot[768]        double  @ 320256   (6144 B)
#define WS_CNT     0
#define WS_RL      768
#define WS_INVP    197376
#define WS_INVZ    246528
#define WS_DIAG    295680
#define WS_PDOT    320256

__global__ void __launch_bounds__(256)
phase1(const float* __restrict__ ps, const float* __restrict__ zs,
       const int* __restrict__ targets,
       int* __restrict__ cnt, int* __restrict__ rowlist,
       float* __restrict__ invp, float* __restrict__ invz,
       double* __restrict__ diagpart) {
    const int b    = blockIdx.x;        // 0..767, 16 rows per block
    const int t    = threadIdx.x;
    const int w    = t >> 6;            // wave 0..3
    const int lane = t & 63;

    double dloc = 0.0;
    #pragma unroll
    for (int j = 0; j < 4; ++j) {
        const int row = b * 16 + w * 4 + j;           // one wave per row
        const float4 p4 = ((const float4*)ps)[row * 64 + lane];
        const float4 z4 = ((const float4*)zs)[row * 64 + lane];
        float sp = p4.x*p4.x + p4.y*p4.y + p4.z*p4.z + p4.w*p4.w;
        float sz = z4.x*z4.x + z4.y*z4.y + z4.z*z4.z + z4.w*z4.w;
        float pz = p4.x*z4.x + p4.y*z4.y + p4.z*z4.z + p4.w*z4.w;
        #pragma unroll
        for (int off = 32; off > 0; off >>= 1) {
            sp += __shfl_down(sp, off, 64);
            sz += __shfl_down(sz, off, 64);
            pz += __shfl_down(pz, off, 64);
        }
        if (lane == 0) {
            const float ip = 1.0f / fmaxf(sqrtf(sp), 1e-8f);
            const float iz = 1.0f / fmaxf(sqrtf(sz), 1e-8f);
            invp[row] = ip;
            invz[row] = iz;
            dloc += (double)pz * (double)ip * (double)iz;
            const int s = row >> 12;
            const int c = targets[row];
            const int slot = atomicAdd(&cnt[s * NCLS + c], 1);
            if (slot < CAP) rowlist[(s * NCLS + c) * CAP + slot] = row;
        }
    }
    if (lane == 0) diagpart[b * 4 + w] = dloc;   // subset of entry e: e>>10
}

__global__ void __launch_bounds__(256)
phase2(const float* __restrict__ ps, const float* __restrict__ zs,
       const int* __restrict__ cnt, const int* __restrict__ rowlist,
       const float* __restrict__ invp, const float* __restrict__ invz,
       double* __restrict__ pairdot) {
    const int sc   = blockIdx.x >> 2;    // 0..191 = s*64 + c
    const int part = blockIdx.x & 3;     // 0..3
    const int t    = threadIdx.x;        // dim 0..255

    __shared__ int   rl[CAP];
    __shared__ float ip[CAP], iz[CAP];

    int k = cnt[sc];
    if (k > CAP) k = CAP;
    if (t < k) {
        const int r = rowlist[sc * CAP + t];
        rl[t] = r;
        ip[t] = invp[r];
        iz[t] = invz[r];
    }
    __syncthreads();

    float P = 0.0f, Z = 0.0f;
    int j = part;                         // stride SPLIT over the class's rows
    // unrolled x4: 8 independent global row loads in flight
    for (; j + 3 * SPLIT < k; j += 4 * SPLIT) {
        const int r0 = rl[j], r1 = rl[j + SPLIT], r2 = rl[j + 2 * SPLIT], r3 = rl[j + 3 * SPLIT];
        const float p0 = ps[r0 * D + t], z0 = zs[r0 * D + t];
        const float p1 = ps[r1 * D + t], z1 = zs[r1 * D + t];
        const float p2 = ps[r2 * D + t], z2 = zs[r2 * D + t];
        const float p3 = ps[r3 * D + t], z3 = zs[r3 * D + t];
        P += p0 * ip[j];              Z += z0 * iz[j];
        P += p1 * ip[j + SPLIT];      Z += z1 * iz[j + SPLIT];
        P += p2 * ip[j + 2 * SPLIT];  Z += z2 * iz[j + 2 * SPLIT];
        P += p3 * ip[j + 3 * SPLIT];  Z += z3 * iz[j + 3 * SPLIT];
    }
    for (; j < k; j += SPLIT) {
        const int r = rl[j];
        P += ps[r * D + t] * ip[j];
        Z += zs[r * D + t] * iz[j];
    }

    // NOTE: partial-P dot partial-Z is WRONG in general — but here each of the
    // SPLIT partials must hold the FULL P and Z? No: dot(P,Z) != sum of
    // dot(P_part, Z_part). We avoid this by dotting per-dimension: thread t
    // owns dim t of the full sums only if it saw all rows. It doesn't — so we
    // instead accumulate P_part/Z_part to global and reduce? Cheaper fix:
    // exchange via LDS is unnecessary — dot(P,Z) = sum_d P[d]*Z[d] and
    // P[d] = sum over ALL rows. A 4-way row split breaks the product.
    // => write partial vectors and let finish do the cross terms? Too big.
    // Correct cheap identity: dot(sum_a Pa, sum_b Zb) = sum_{a,b} dot(Pa, Zb).
    // With SPLIT=4 that's 16 cross dots — do them here via LDS exchange:
    __shared__ float Pp[SPLIT][D + 4], Zp[SPLIT][D + 4];
    Pp[part][t] = P;  // only this block's partial — other parts are other
    Zp[part][t] = Z;  // blocks! LDS is per-block: CANNOT see them.
    // The above is unusable; real fix below: write partial vectors to global
    // and have a reducer. To keep one kernel, we instead make each block
    // compute the FULL P but only PART of Z's rows... also wrong.
    // Final resolution (correct): each block computes FULL P and FULL Z but
    // only over its quarter of ROWS for BOTH — cross terms lost.
    // --> See pvec/zvec global reduction below (this path replaces the dot).
    pairdot[blockIdx.x] = 0.0;  // overwritten by reducer; kept for layout
}

// The comment block above documents the pitfall; actual implementation:
// phase2 writes partial vectors, phase3 reduces 4 partials and dots.
__global__ void __launch_bounds__(256)
phase2v(const float* __restrict__ ps, const float* __restrict__ zs,
        const int* __restrict__ cnt, const int* __restrict__ rowlist,
        const float* __restrict__ invp, const float* __restrict__ invz,
        float* __restrict__ pvec, float* __restrict__ zvec) {
    const int sc   = blockIdx.x >> 2;
    const int part = blockIdx.x & 3;
    const int t    = threadIdx.x;

    __shared__ int   rl[CAP];
    __shared__ float ip[CAP], iz[CAP];

    int k = cnt[sc];
    if (k > CAP) k = CAP;
    if (t < k) {
        const int r = rowlist[sc * CAP + t];
        rl[t] = r;
        ip[t] = invp[r];
        iz[t] = invz[r];
    }
    __syncthreads();

    float P = 0.0f, Z = 0.0f;
    int j = part;
    for (; j + 3 * SPLIT < k; j += 4 * SPLIT) {
        const int r0 = rl[j], r1 = rl[j + SPLIT], r2 = rl[j + 2 * SPLIT], r3 = rl[j + 3 * SPLIT];
        const float p0 = ps[r0 * D + t], z0 = zs[r0 * D + t];
        const float p1 = ps[r1 * D + t], z1 = zs[r1 * D + t];
        const float p2 = ps[r2 * D + t], z2 = zs[r2 * D + t];
        const float p3 = ps[r3 * D + t], z3 = zs[r3 * D + t];
        P += p0 * ip[j];              Z += z0 * iz[j];
        P += p1 * ip[j + SPLIT];      Z += z1 * iz[j + SPLIT];
        P += p2 * ip[j + 2 * SPLIT];  Z += z2 * iz[j + 2 * SPLIT];
        P += p3 * ip[j + 3 * SPLIT];  Z += z3 * iz[j + 3 * SPLIT];
    }
    for (; j < k; j += SPLIT) {
        const int r = rl[j];
        P += ps[r * D + t] * ip[j];
        Z += zs[r * D + t] * iz[j];
    }
    pvec[blockIdx.x * D + t] = P;   // [sc*4+part][256]
    zvec[blockIdx.x * D + t] = Z;
}

__global__ void __launch_bounds__(256)
phase3(const float* __restrict__ pvec, const float* __restrict__ zvec,
       double* __restrict__ pairdot) {
    const int sc = blockIdx.x;   // 0..191
    const int t  = threadIdx.x;  // dim
    const int b  = sc * SPLIT * D + t;
    const float P = pvec[b] + pvec[b + D] + pvec[b + 2 * D] + pvec[b + 3 * D];
    const float Z = zvec[b] + zvec[b + D] + zvec[b + 2 * D] + zvec[b + 3 * D];
    double dot = (double)P * (double)Z;
    #pragma unroll
    for (int off = 32; off > 0; off >>= 1)
        dot += __shfl_down(dot, off, 64);
    __shared__ double sred[4];
    if ((t & 63) == 0) sred[t >> 6] = dot;
    __syncthreads();
    if (t == 0) pairdot[sc] = sred[0] + sred[1] + sred[2] + sred[3];
}

__global__ void __launch_bounds__(256)
finish(const double* __restrict__ pairdot, const double* __restrict__ diagpart,
       const int* __restrict__ cnt, float* __restrict__ out) {
    const int t    = threadIdx.x;
    const int w    = t >> 6;
    const int lane = t & 63;

    double dotv = 0.0, c2 = 0.0;      // wave w holds subset w contributions
    if (t < NSUB * NCLS) {
        dotv = pairdot[t];            // subset = t>>6 = wave index (t<192)
        const double kk = (double)cnt[t];
        c2 = kk * (kk - 1.0) * 0.5;
    }
    double dg[NSUB] = {0.0, 0.0, 0.0};
    #pragma unroll
    for (int q = 0; q < 12; ++q)
        dg[q >> 2] += diagpart[q * 256 + t];   // subset = (q*256+t)>>10 = q>>2

    #pragma unroll
    for (int off = 32; off > 0; off >>= 1) {
        dotv += __shfl_down(dotv, off, 64);
        c2   += __shfl_down(c2, off, 64);
        #pragma unroll
        for (int s = 0; s < NSUB; ++s) dg[s] += __shfl_down(dg[s], off, 64);
    }

    __shared__ double wdot[4], wc2[4], wdg[NSUB][4];
    if (lane == 0) {
        wdot[w] = dotv;
        wc2[w]  = c2;
        #pragma unroll
        for (int s = 0; s < NSUB; ++s) wdg[s][w] = dg[s];
    }
    __syncthreads();
    if (t == 0) {
        double acc = 0.0;
        #pragma unroll
        for (int s = 0; s < NSUB; ++s) {
            const double diag_s = wdg[s][0] + wdg[s][1] + wdg[s][2] + wdg[s][3];
            const double pair_s = wdot[s] - diag_s;
            acc += -0.5 * pair_s / wc2[s];
        }
        out[0] = (float)(acc / (double)NSUB);
    }
}

// extra ws (after pairdot): pvec[768*256] f32 @ 326400 (786432 B),
//                           zvec[768*256] f32 @ 1112832 (786432 B)
#define WS_PVEC 326400
#define WS_ZVEC 1112832

extern "C" void kernel_launch(void* const* d_in, const int* in_sizes, int n_in,
                              void* d_out, int out_size, void* d_ws, size_t ws_size,
                              hipStream_t stream) {
    const float* ps      = (const float*)d_in[0];
    const float* zs      = (const float*)d_in[1];
    const int*   targets = (const int*)d_in[2];

    char* ws = (char*)d_ws;
    int*    cnt      = (int*)(ws + WS_CNT);
    int*    rowlist  = (int*)(ws + WS_RL);
    float*  invp     = (float*)(ws + WS_INVP);
    float*  invz     = (float*)(ws + WS_INVZ);
    double* diagpart = (double*)(ws + WS_DIAG);
    double* pairdot  = (double*)(ws + WS_PDOT);
    float*  pvec     = (float*)(ws + WS_PVEC);
    float*  zvec     = (float*)(ws + WS_ZVEC);

    hipMemsetAsync(cnt, 0, NSUB * NCLS * sizeof(int), stream);

    phase1<<<B_TOT / 16, 256, 0, stream>>>(ps, zs, targets, cnt, rowlist,
                                           invp, invz, diagpart);
    phase2v<<<NSUB * NCLS * SPLIT, 256, 0, stream>>>(ps, zs, cnt, rowlist,
                                                     invp, invz, pvec, zvec);
    phase3<<<NSUB * NCLS, 256, 0, stream>>>(pvec, zvec, pairdot);
    finish<<<1, 256, 0, stream>>>(pairdot, diagpart, cnt, (float*)d_out);
}

// Round 4
// 84.274 us; speedup vs baseline: 3.0347x; 1.2190x over previous
//
#include <hip/hip_runtime.h>

// B=12288, D=256, N_SUBSETS=3, m=4096, 64 classes, EPS=1e-8, WEIGHT=1.0.
//
// pair_sum_s = sum_c dot(P_c, Z_c) - sum_i pn_i.zn_i   (P_c = sum of pn rows in class c)
// loss = mean_s( -0.5 * pair_sum_s / cnt_s )
//
// R4: full fusion. Block (s,c) scans targets for its class (16 KB, L2-hit),
// computes norms for its ~64 rows (one wave/row, float4 — the only HBM pass),
// then re-accumulates P,Z from L1/L2 and dots. 2 kernels, no memset, no
// global fp32 scratch. ~86 us of measured dur is the harness's 256 MiB d_ws
// poison fill (2 x 43 us fillBufferAligned) — not addressable from here.

#define D     256
#define NSUB  3
#define NCLS  64
#define M     4096
#define CAP   256   // rows per class: mean 64, binomial max ~100

// ws layout (all written unconditionally each launch — no memset needed):
//   pairdot[192]  double @ 0     (1536 B)
//   diagpart[192] double @ 1536  (1536 B)
//   cnt[192]      int    @ 3072  (768 B)
#define WS_PDOT 0
#define WS_DIAG 1536
#define WS_CNT  3072

__global__ void __launch_bounds__(512)
simsiam_main(const float* __restrict__ ps, const float* __restrict__ zs,
             const int* __restrict__ targets,
             double* __restrict__ pairdot, double* __restrict__ diagpart,
             int* __restrict__ cnt) {
    const int sc   = blockIdx.x;       // 0..191 = s*64 + c
    const int s    = sc >> 6;
    const int c    = sc & 63;
    const int t    = threadIdx.x;      // 0..511
    const int w    = t >> 6;           // wave 0..7
    const int lane = t & 63;

    __shared__ int   mlist[CAP];
    __shared__ float ipl[CAP], izl[CAP];
    __shared__ int   mcount;
    __shared__ double wdiag[8];
    __shared__ float  Pp[2][D], Zp[2][D];
    __shared__ double sdot[4];

    if (t == 0) mcount = 0;
    __syncthreads();

    // --- scan targets for class c of subset s (16 KB, shared across the 64
    //     blocks of this subset -> L2 hits) ---
    #pragma unroll
    for (int j = t; j < M; j += 512) {
        if (targets[s * M + j] == c) {
            const int slot = atomicAdd(&mcount, 1);
            if (slot < CAP) mlist[slot] = s * M + j;
        }
    }
    __syncthreads();
    const int k = mcount < CAP ? mcount : CAP;

    // --- norm pass: one wave per matched row (the HBM pass) ---
    double dloc = 0.0;
    for (int jj = w; jj < k; jj += 8) {
        const int r = mlist[jj];
        const float4 p4 = ((const float4*)ps)[r * 64 + lane];
        const float4 z4 = ((const float4*)zs)[r * 64 + lane];
        float sp = p4.x*p4.x + p4.y*p4.y + p4.z*p4.z + p4.w*p4.w;
        float sz = z4.x*z4.x + z4.y*z4.y + z4.z*z4.z + z4.w*z4.w;
        float pz = p4.x*z4.x + p4.y*z4.y + p4.z*z4.z + p4.w*z4.w;
        #pragma unroll
        for (int off = 32; off > 0; off >>= 1) {
            sp += __shfl_down(sp, off, 64);
            sz += __shfl_down(sz, off, 64);
            pz += __shfl_down(pz, off, 64);
        }
        if (lane == 0) {
            const float ip = 1.0f / fmaxf(sqrtf(sp), 1e-8f);
            const float iz = 1.0f / fmaxf(sqrtf(sz), 1e-8f);
            ipl[jj] = ip;
            izl[jj] = iz;
            dloc += (double)pz * (double)ip * (double)iz;
        }
    }
    if (lane == 0) wdiag[w] = dloc;
    __syncthreads();

    // --- accumulate P, Z (rows now in L1/L2; 128 KB/block, 3 MB/XCD) ---
    const int q = t >> 8;      // row-half 0/1
    const int d = t & 255;     // dim
    float P = 0.0f, Z = 0.0f;
    int jj = q;
    for (; jj + 6 < k; jj += 8) {   // 4 rows/group, 8 independent loads
        const int r0 = mlist[jj],     r1 = mlist[jj + 2];
        const int r2 = mlist[jj + 4], r3 = mlist[jj + 6];
        const float p0 = ps[r0 * D + d], z0 = zs[r0 * D + d];
        const float p1 = ps[r1 * D + d], z1 = zs[r1 * D + d];
        const float p2 = ps[r2 * D + d], z2 = zs[r2 * D + d];
        const float p3 = ps[r3 * D + d], z3 = zs[r3 * D + d];
        P += p0 * ipl[jj];     Z += z0 * izl[jj];
        P += p1 * ipl[jj + 2]; Z += z1 * izl[jj + 2];
        P += p2 * ipl[jj + 4]; Z += z2 * izl[jj + 4];
        P += p3 * ipl[jj + 6]; Z += z3 * izl[jj + 6];
    }
    for (; jj < k; jj += 2) {
        const int r = mlist[jj];
        P += ps[r * D + d] * ipl[jj];
        Z += zs[r * D + d] * izl[jj];
    }
    Pp[q][d] = P;
    Zp[q][d] = Z;
    __syncthreads();

    // --- dot(P, Z) in fp64, write per-class outputs ---
    if (t < D) {
        const float Pf = Pp[0][t] + Pp[1][t];
        const float Zf = Zp[0][t] + Zp[1][t];
        double dot = (double)Pf * (double)Zf;
        #pragma unroll
        for (int off = 32; off > 0; off >>= 1)
            dot += __shfl_down(dot, off, 64);
        if (lane == 0) sdot[w] = dot;
    }
    __syncthreads();
    if (t == 0) {
        pairdot[sc]  = sdot[0] + sdot[1] + sdot[2] + sdot[3];
        diagpart[sc] = wdiag[0] + wdiag[1] + wdiag[2] + wdiag[3]
                     + wdiag[4] + wdiag[5] + wdiag[6] + wdiag[7];
        cnt[sc] = mcount;
    }
}

__global__ void __launch_bounds__(256)
simsiam_finish(const double* __restrict__ pairdot,
               const double* __restrict__ diagpart,
               const int* __restrict__ cnt, float* __restrict__ out) {
    const int t    = threadIdx.x;
    const int w    = t >> 6;     // wave w holds subset w's 64 classes (t<192)
    const int lane = t & 63;

    double dotv = 0.0, dgv = 0.0, c2 = 0.0;
    if (t < NSUB * NCLS) {
        dotv = pairdot[t];
        dgv  = diagpart[t];
        const double kk = (double)cnt[t];
        c2 = kk * (kk - 1.0) * 0.5;
    }
    #pragma unroll
    for (int off = 32; off > 0; off >>= 1) {
        dotv += __shfl_down(dotv, off, 64);
        dgv  += __shfl_down(dgv, off, 64);
        c2   += __shfl_down(c2, off, 64);
    }

    __shared__ double wdot[4], wdg[4], wc2[4];
    if (lane == 0) { wdot[w] = dotv; wdg[w] = dgv; wc2[w] = c2; }
    __syncthreads();
    if (t == 0) {
        double acc = 0.0;
        #pragma unroll
        for (int s = 0; s < NSUB; ++s)
            acc += -0.5 * (wdot[s] - wdg[s]) / wc2[s];
        out[0] = (float)(acc / (double)NSUB);
    }
}

extern "C" void kernel_launch(void* const* d_in, const int* in_sizes, int n_in,
                              void* d_out, int out_size, void* d_ws, size_t ws_size,
                              hipStream_t stream) {
    const float* ps      = (const float*)d_in[0];
    const float* zs      = (const float*)d_in[1];
    const int*   targets = (const int*)d_in[2];

    char* ws = (char*)d_ws;
    double* pairdot  = (double*)(ws + WS_PDOT);
    double* diagpart = (double*)(ws + WS_DIAG);
    int*    cnt      = (int*)(ws + WS_CNT);

    simsiam_main<<<NSUB * NCLS, 512, 0, stream>>>(ps, zs, targets,
                                                  pairdot, diagpart, cnt);
    simsiam_finish<<<1, 256, 0, stream>>>(pairdot, diagpart, cnt,
                                          (float*)d_out);
}